// Round 12
// baseline (181.860 us; speedup 1.0000x reference)
//
#include <hip/hip_runtime.h>

#define SEQ_L 1024
#define BATCH_N 512
#define NTAG 48

typedef __fp16 h2v __attribute__((ext_vector_type(2)));
typedef __fp16 h4v __attribute__((ext_vector_type(4)));
typedef float f4v __attribute__((ext_vector_type(4)));

__device__ inline h4v pk4(float a, float b, float c, float d) {
    h2v lo = __builtin_amdgcn_cvt_pkrtz(a, b);
    h2v hi = __builtin_amdgcn_cvt_pkrtz(c, d);
    return __builtin_shufflevector(lo, hi, 0, 1, 2, 3);
}

__device__ inline float wave_sum_f(float v) {
    #pragma unroll
    for (int off = 32; off > 0; off >>= 1) v += __shfl_xor(v, off, 64);
    return v;
}
__device__ inline int wave_sum_i(int v) {
    #pragma unroll
    for (int off = 32; off > 0; off >>= 1) v += __shfl_xor(v, off, 64);
    return v;
}

// column-sum across the 4 row-groups (cold path only)
__device__ inline float colsum4(float part) {
    part += __shfl_xor(part, 16, 64);
    part += __shfl_xor(part, 32, 64);
    return part;
}

#define MFMA16 __builtin_amdgcn_mfma_f32_16x16x16f16

// ---- prefetch: 8 named buffers, each {3 x float4 emissions, 1 mask}
#define PFDECL(B) f4v p##B##e0, p##B##e1, p##B##e2; int p##B##m;
#define PF(B, IT) {                                                            \
    int it2_ = (IT) > 511 ? 511 : (IT);                                        \
    int idx_ = fwd ? it2_ : (1023 - it2_);                                     \
    const float* p_ = em + (size_t)idx_ * (BATCH_N * NTAG) + laneoff;          \
    p##B##e0 = *(const f4v*)(p_);                                              \
    p##B##e1 = *(const f4v*)(p_ + 16);                                         \
    p##B##e2 = *(const f4v*)(p_ + 32);                                         \
    int m_ = maskp[idx_ * BATCH_N + bb + c];                                   \
    p##B##m = (fwd && idx_ == 0) ? 0 : m_;                                     \
}

// fwd step (round-10 numerics, shortened chains):
// C = E^T X (2-chain + 1 parallel per tile), Cs = colsum(C) via A4,
// X' = C o F / Cs   (entries bounded by maxF — unconditionally fp16-safe)
// invariant: alpha_true = X * e^ls
#define STEP_F(B) {                                                            \
    f4v F0, F1, F2;                                                            \
    _Pragma("unroll") for (int j = 0; j < 4; ++j) {                            \
        F0[j] = __expf(p##B##e0[j]);                                           \
        F1[j] = __expf(p##B##e1[j]);                                           \
        F2[j] = __expf(p##B##e2[j]);                                           \
    }                                                                          \
    f4v t01_ = MFMA16(A41, Bf1, MFMA16(A40, Bf0, kz, 0, 0, 0), 0, 0, 0);       \
    f4v t2_  = MFMA16(A42, Bf2, kz, 0, 0, 0);                                  \
    f4v c01_ = MFMA16(A01, Bf1, MFMA16(A00, Bf0, kz, 0, 0, 0), 0, 0, 0);       \
    f4v c2_  = MFMA16(A02, Bf2, kz, 0, 0, 0);                                  \
    f4v d01_ = MFMA16(A11, Bf1, MFMA16(A10, Bf0, kz, 0, 0, 0), 0, 0, 0);       \
    f4v d2_  = MFMA16(A12, Bf2, kz, 0, 0, 0);                                  \
    f4v e01_ = MFMA16(A21, Bf1, MFMA16(A20, Bf0, kz, 0, 0, 0), 0, 0, 0);       \
    f4v e2_  = MFMA16(A22, Bf2, kz, 0, 0, 0);                                  \
    float s_ = t01_[0] + t2_[0];                                               \
    float inv_ = __builtin_amdgcn_rcpf(s_);                                    \
    f4v C0 = c01_ + c2_;                                                       \
    f4v C1 = d01_ + d2_;                                                       \
    f4v C2 = e01_ + e2_;                                                       \
    f4v W0 = F0 * inv_, W1 = F1 * inv_, W2 = F2 * inv_;                        \
    f4v X0 = C0 * W0, X1 = C1 * W1, X2 = C2 * W2;                              \
    h4v n0_ = pk4(X0[0], X0[1], X0[2], X0[3]);                                 \
    h4v n1_ = pk4(X1[0], X1[1], X1[2], X1[3]);                                 \
    h4v n2_ = pk4(X2[0], X2[1], X2[2], X2[3]);                                 \
    bool mk_ = p##B##m != 0;                                                   \
    Bf0 = mk_ ? n0_ : Bf0;                                                     \
    Bf1 = mk_ ? n1_ : Bf1;                                                     \
    Bf2 = mk_ ? n2_ : Bf2;                                                     \
    ls += mk_ ? __logf(s_) : 0.0f;                                             \
}

// bwd step (round-10 numerics): Y = S o F * inv_pending, pack,
// S' = E Y, Cs = colsum(S') via A4 -> next inv.  invariant: u = S * inv * e^ls
#define STEP_B(B) {                                                            \
    f4v F0, F1, F2;                                                            \
    _Pragma("unroll") for (int j = 0; j < 4; ++j) {                            \
        F0[j] = __expf(p##B##e0[j]);                                           \
        F1[j] = __expf(p##B##e1[j]);                                           \
        F2[j] = __expf(p##B##e2[j]);                                           \
    }                                                                          \
    f4v W0 = F0 * inv, W1 = F1 * inv, W2 = F2 * inv;                           \
    f4v Y0 = S0 * W0, Y1 = S1 * W1, Y2 = S2 * W2;                              \
    h4v b0_ = pk4(Y0[0], Y0[1], Y0[2], Y0[3]);                                 \
    h4v b1_ = pk4(Y1[0], Y1[1], Y1[2], Y1[3]);                                 \
    h4v b2_ = pk4(Y2[0], Y2[1], Y2[2], Y2[3]);                                 \
    f4v t01_ = MFMA16(A41, b1_, MFMA16(A40, b0_, kz, 0, 0, 0), 0, 0, 0);       \
    f4v t2_  = MFMA16(A42, b2_, kz, 0, 0, 0);                                  \
    f4v c01_ = MFMA16(A01, b1_, MFMA16(A00, b0_, kz, 0, 0, 0), 0, 0, 0);       \
    f4v c2_  = MFMA16(A02, b2_, kz, 0, 0, 0);                                  \
    f4v d01_ = MFMA16(A11, b1_, MFMA16(A10, b0_, kz, 0, 0, 0), 0, 0, 0);       \
    f4v d2_  = MFMA16(A12, b2_, kz, 0, 0, 0);                                  \
    f4v e01_ = MFMA16(A21, b1_, MFMA16(A20, b0_, kz, 0, 0, 0), 0, 0, 0);       \
    f4v e2_  = MFMA16(A22, b2_, kz, 0, 0, 0);                                  \
    float s_ = t01_[0] + t2_[0];                                               \
    f4v N0 = c01_ + c2_;                                                       \
    f4v N1 = d01_ + d2_;                                                       \
    f4v N2 = e01_ + e2_;                                                       \
    bool mk_ = p##B##m != 0;                                                   \
    float ninv_ = __builtin_amdgcn_rcpf(s_);                                   \
    S0 = mk_ ? N0 : S0;                                                        \
    S1 = mk_ ? N1 : S1;                                                        \
    S2 = mk_ ? N2 : S2;                                                        \
    inv = mk_ ? ninv_ : inv;                                                   \
    ls += mk_ ? __logf(s_) : 0.0f;                                             \
}

__attribute__((amdgpu_flat_work_group_size(128,128), amdgpu_waves_per_eu(1,2)))
__global__ void crf_scan_kernel(
    const float* __restrict__ em,
    const float* __restrict__ start_t,
    const float* __restrict__ end_t,
    const float* __restrict__ trans,
    const int*   __restrict__ maskp,
    float*       __restrict__ z_out) {
    const int bb = blockIdx.x * 16;        // batch tile base
    const int w = threadIdx.x >> 6;        // 0 = fwd wave, 1 = bwd wave
    const bool fwd = (w == 0);
    const int lane = threadIdx.x & 63;
    const int c = lane & 15;               // batch column
    const int g = lane >> 4;               // row group

    __shared__ float shX[NTAG][17];
    __shared__ float shL[16];
    __shared__ float sh_w4[2][NTAG];

    // cooperative w4: fwd wave needs rowsum of E, bwd wave colsum of E
    if (lane < NTAG) {
        float s = 0.f;
        #pragma unroll 8
        for (int t2 = 0; t2 < NTAG; ++t2)
            s += __expf(trans[fwd ? (lane * NTAG + t2) : (t2 * NTAG + lane)]);
        sh_w4[w][lane] = s;
    }
    __syncthreads();

    // ---- constant A fragments (verified mapping, rounds 9-10):
    // fwd A=E^T (A[m][k]=E[k][m]); bwd A=E.  m = lane&15, k = 16*KT + 4*g + j.
    h4v A00, A01, A02, A10, A11, A12, A20, A21, A22, A40, A41, A42;
    {
        #define LOADA(MT, KT, DST) {                                           \
            float e_[4];                                                       \
            _Pragma("unroll") for (int j = 0; j < 4; ++j) {                    \
                int kidx_ = 16*(KT) + 4*g + j;                                 \
                int midx_ = 16*(MT) + c;                                       \
                int r_ = fwd ? kidx_ : midx_;                                  \
                int cc_ = fwd ? midx_ : kidx_;                                 \
                e_[j] = __expf(trans[r_ * NTAG + cc_]);                        \
            }                                                                  \
            DST = pk4(e_[0], e_[1], e_[2], e_[3]);                             \
        }
        #define LOADA4(KT, DST) {                                              \
            float e_[4];                                                       \
            _Pragma("unroll") for (int j = 0; j < 4; ++j)                      \
                e_[j] = sh_w4[w][16*(KT) + 4*g + j];                           \
            DST = pk4(e_[0], e_[1], e_[2], e_[3]);                             \
        }
        LOADA(0,0,A00) LOADA(0,1,A01) LOADA(0,2,A02)
        LOADA(1,0,A10) LOADA(1,1,A11) LOADA(1,2,A12)
        LOADA(2,0,A20) LOADA(2,1,A21) LOADA(2,2,A22)
        LOADA4(0,A40)  LOADA4(1,A41)  LOADA4(2,A42)
        #undef LOADA
        #undef LOADA4
    }

    const f4v kz = {0.f, 0.f, 0.f, 0.f};
    const size_t laneoff = (size_t)(bb + c) * NTAG + (size_t)g * 4;

    // ---- state
    h4v Bf0, Bf1, Bf2;        // fwd: X fp16 B-fragments (col-normalized-ish)
    f4v S0, S1, S2;           // bwd: f32 C-layout state
    float inv = 1.0f;         // bwd pending reciprocal scale
    float ls = 0.0f;          // accumulated log-scale

    if (fwd) {
        f4v e0 = *(const f4v*)(em + laneoff);
        f4v e1 = *(const f4v*)(em + laneoff + 16);
        f4v e2 = *(const f4v*)(em + laneoff + 32);
        float x0[4], x1[4], x2[4];
        float psum = 0.f;
        #pragma unroll
        for (int j = 0; j < 4; ++j) {
            x0[j] = __expf(start_t[ 0 + 4*g + j] + e0[j]);
            x1[j] = __expf(start_t[16 + 4*g + j] + e1[j]);
            x2[j] = __expf(start_t[32 + 4*g + j] + e2[j]);
            psum += x0[j] + x1[j] + x2[j];
        }
        float s0 = colsum4(psum);           // cold one-time normalize
        float inv0 = 1.0f / s0;
        ls = __logf(s0);
        Bf0 = pk4(x0[0]*inv0, x0[1]*inv0, x0[2]*inv0, x0[3]*inv0);
        Bf1 = pk4(x1[0]*inv0, x1[1]*inv0, x1[2]*inv0, x1[3]*inv0);
        Bf2 = pk4(x2[0]*inv0, x2[1]*inv0, x2[2]*inv0, x2[3]*inv0);
    } else {
        #pragma unroll
        for (int j = 0; j < 4; ++j) {
            S0[j] = __expf(end_t[ 0 + 4*g + j]);
            S1[j] = __expf(end_t[16 + 4*g + j]);
            S2[j] = __expf(end_t[32 + 4*g + j]);
        }
    }

    // ---- main scan: 512 iterations, 8-deep prefetch
    PFDECL(0) PFDECL(1) PFDECL(2) PFDECL(3)
    PFDECL(4) PFDECL(5) PFDECL(6) PFDECL(7)
    PF(0,0) PF(1,1) PF(2,2) PF(3,3) PF(4,4) PF(5,5) PF(6,6) PF(7,7)
    if (fwd) {
        #pragma unroll 1
        for (int i = 0; i < 512; i += 8) {
            STEP_F(0) PF(0, i + 8)
            STEP_F(1) PF(1, i + 9)
            STEP_F(2) PF(2, i + 10)
            STEP_F(3) PF(3, i + 11)
            STEP_F(4) PF(4, i + 12)
            STEP_F(5) PF(5, i + 13)
            STEP_F(6) PF(6, i + 14)
            STEP_F(7) PF(7, i + 15)
        }
    } else {
        #pragma unroll 1
        for (int i = 0; i < 512; i += 8) {
            STEP_B(0) PF(0, i + 8)
            STEP_B(1) PF(1, i + 9)
            STEP_B(2) PF(2, i + 10)
            STEP_B(3) PF(3, i + 11)
            STEP_B(4) PF(4, i + 12)
            STEP_B(5) PF(5, i + 13)
            STEP_B(6) PF(6, i + 14)
            STEP_B(7) PF(7, i + 15)
        }
    }

    // ---- combine:  logZ_b = lsF + lsB + log( inv_b * sum_t X[t,b]*S[t,b] )
    if (fwd) {
        #pragma unroll
        for (int j = 0; j < 4; ++j) {
            shX[ 0 + 4*g + j][c] = (float)Bf0[j];
            shX[16 + 4*g + j][c] = (float)Bf1[j];
            shX[32 + 4*g + j][c] = (float)Bf2[j];
        }
        if (lane < 16) shL[lane] = ls;
    }
    __syncthreads();
    if (!fwd) {
        float d = 0.f;
        #pragma unroll
        for (int j = 0; j < 4; ++j) {
            d += S0[j] * shX[ 0 + 4*g + j][c];
            d += S1[j] * shX[16 + 4*g + j][c];
            d += S2[j] * shX[32 + 4*g + j][c];
        }
        d = colsum4(d);
        float logz = shL[c] + ls + __logf(d * inv);
        if (lane < 16) z_out[bb + lane] = logz;
    }
}

__global__ __launch_bounds__(64) void crf_num_kernel(
    const float* __restrict__ em,
    const float* __restrict__ start_t,
    const float* __restrict__ end_t,
    const float* __restrict__ trans,
    const int*   __restrict__ tags,
    const int*   __restrict__ maskp,
    float*       __restrict__ num_out) {
    const int b = blockIdx.x;
    const int lane = threadIdx.x;
    float numpart = 0.0f;
    int cnt = 0;
    #pragma unroll 4
    for (int jj = 0; jj < 16; ++jj) {
        int i = jj * 64 + lane;
        int tag_i = tags[(size_t)i * BATCH_N + b];
        int m = maskp[i * BATCH_N + b];
        cnt += (m != 0);
        if (i == 0) {
            numpart += start_t[tag_i] + em[(size_t)b * NTAG + tag_i];
        } else if (m) {
            int tag_p = tags[(size_t)(i - 1) * BATCH_N + b];
            numpart += trans[tag_p * NTAG + tag_i] +
                       em[((size_t)i * BATCH_N + b) * NTAG + tag_i];
        }
    }
    float num = wave_sum_f(numpart);
    int seq_len = wave_sum_i(cnt);
    int last_tag = tags[(size_t)(seq_len - 1) * BATCH_N + b];
    if (lane == 0) num_out[b] = num + end_t[last_tag];
}

__global__ __launch_bounds__(512) void final_reduce_kernel(
    const float* __restrict__ z, const float* __restrict__ num,
    float* __restrict__ out) {
    float x = z[threadIdx.x] - num[threadIdx.x];   // = -llh[b]
    x = wave_sum_f(x);
    __shared__ float ws[8];
    int w = threadIdx.x >> 6;
    if ((threadIdx.x & 63) == 0) ws[w] = x;
    __syncthreads();
    if (threadIdx.x == 0) {
        float t = 0.0f;
        #pragma unroll
        for (int k = 0; k < 8; ++k) t += ws[k];
        *out = t;
    }
}

extern "C" void kernel_launch(void* const* d_in, const int* in_sizes, int n_in,
                              void* d_out, int out_size, void* d_ws, size_t ws_size,
                              hipStream_t stream) {
    const float* emissions = (const float*)d_in[0];
    const float* start_t   = (const float*)d_in[1];
    const float* end_t     = (const float*)d_in[2];
    const float* trans     = (const float*)d_in[3];
    const int*   tags      = (const int*)d_in[4];
    const int*   mask      = (const int*)d_in[5];
    float* z_ws   = (float*)d_ws;            // [512]
    float* num_ws = z_ws + BATCH_N;          // [512]

    crf_scan_kernel<<<BATCH_N / 16, 128, 0, stream>>>(emissions, start_t, end_t,
                                                      trans, mask, z_ws);
    crf_num_kernel<<<BATCH_N, 64, 0, stream>>>(emissions, start_t, end_t, trans,
                                               tags, mask, num_ws);
    final_reduce_kernel<<<1, 512, 0, stream>>>(z_ws, num_ws, (float*)d_out);
}